// Round 1
// baseline (227.409 us; speedup 1.0000x reference)
//
#include <hip/hip_runtime.h>

// Problem constants (from setup_inputs: B=4, T=8192, C=1024, stride=2)
#define NB 4
#define NT 8192
#define NC 1024
#define W0C 128
#define W1C 64
#define W2C 16
#define NCHUNKS ((NT - W0C) / 2) // 4032
#define NPAIRS (W1C / 2)         // 32

// Output layout (flat f32 offsets): K0,V0,K1,V1,K2,V2,total_recon
#define OFF_K0 0
#define OFF_V0 (NB * W0C * NC)             // 524288
#define OFF_K1 (2 * NB * W0C * NC)         // 1048576
#define OFF_V1 (OFF_K1 + NB * W1C * NC)    // 1310720
#define OFF_K2 (OFF_V1 + NB * W1C * NC)    // 1572864
#define OFF_V2 (OFF_K2 + NB * W2C * NC)    // 1638400
#define OFF_R  (OFF_V2 + NB * W2C * NC)    // 1703936

__device__ __forceinline__ float dot4(float4 a, float4 b) {
    return a.x * b.x + a.y * b.y + a.z * b.z + a.w * b.w;
}

// K0/V0: copy last W0 rows of K and V. 2 * B*W0*C/4 float4s = 262144.
__global__ __launch_bounds__(256) void copy0_kernel(const float* __restrict__ K,
                                                    const float* __restrict__ V,
                                                    float* __restrict__ out) {
    int idx = blockIdx.x * 256 + threadIdx.x; // float4 index
    const int half = NB * W0C * NC / 4;       // 131072
    const float* src;
    float* dst;
    int i;
    if (idx < half) { src = K; dst = out + OFF_K0; i = idx; }
    else            { src = V; dst = out + OFF_V0; i = idx - half; }
    const int per_b = W0C * NC / 4; // 32768 float4 per batch
    int b = i / per_b;
    int r = i - b * per_b;
    const float4* s4 = (const float4*)(src + ((size_t)b * NT + (NT - W0C)) * NC);
    ((float4*)dst)[i] = s4[r];
}

// Level-1 pool: one block per (b, n) chunk. 256 threads, 4 channels/thread.
__global__ __launch_bounds__(256) void pool1_kernel(const float* __restrict__ K,
                                                    const float* __restrict__ V,
                                                    const float* __restrict__ q,
                                                    float* __restrict__ out) {
    const int n = blockIdx.x;
    const int b = blockIdx.y;
    const int tid = threadIdx.x;

    const size_t row0 = ((size_t)b * NT + 2 * n) * NC;
    const float4 k0 = ((const float4*)(K + row0))[tid];
    const float4 k1 = ((const float4*)(K + row0 + NC))[tid];
    const float4 v0 = ((const float4*)(V + row0))[tid];
    const float4 v1 = ((const float4*)(V + row0 + NC))[tid];
    const float4 q4 = ((const float4*)q)[tid];

    float s0 = dot4(q4, k0);
    float s1 = dot4(q4, k1);
    float4 dv = make_float4(v0.x - v1.x, v0.y - v1.y, v0.z - v1.z, v0.w - v1.w);
    float d2 = dot4(dv, dv);

#pragma unroll
    for (int off = 32; off > 0; off >>= 1) {
        s0 += __shfl_down(s0, off);
        s1 += __shfl_down(s1, off);
        d2 += __shfl_down(d2, off);
    }

    __shared__ float lds[12];
    __shared__ float wshare;
    const int lane = tid & 63, wv = tid >> 6;
    if (lane == 0) { lds[wv] = s0; lds[4 + wv] = s1; lds[8 + wv] = d2; }
    __syncthreads();
    if (tid == 0) {
        float t0 = lds[0] + lds[1] + lds[2] + lds[3];
        float t1 = lds[4] + lds[5] + lds[6] + lds[7];
        float td = lds[8] + lds[9] + lds[10] + lds[11];
        float w0 = 1.0f / (1.0f + expf(t1 - t0)); // softmax over 2
        wshare = w0;
        float dw = w0 - 0.5f;
        // recon1[n] contribution: dw^2 * sum_c diff^2 / (B*C); total += sum_n / NCHUNKS
        atomicAdd(out + OFF_R, dw * dw * td * (1.0f / ((float)NB * NC * NCHUNKS)));
    }
    __syncthreads();

    if (n >= NCHUNKS - W1C) {
        const float w0 = wshare, w1 = 1.0f - w0;
        const int nn = n - (NCHUNKS - W1C);
        float4 sk = make_float4(w0 * k0.x + w1 * k1.x, w0 * k0.y + w1 * k1.y,
                                w0 * k0.z + w1 * k1.z, w0 * k0.w + w1 * k1.w);
        float4 sv = make_float4(w0 * v0.x + w1 * v1.x, w0 * v0.y + w1 * v1.y,
                                w0 * v0.z + w1 * v1.z, w0 * v0.w + w1 * v1.w);
        ((float4*)(out + OFF_K1 + ((size_t)b * W1C + nn) * NC))[tid] = sk;
        ((float4*)(out + OFF_V1 + ((size_t)b * W1C + nn) * NC))[tid] = sv;
    }
}

// Level-2 pool: reads K1/V1 from out (stream-ordered after pool1).
__global__ __launch_bounds__(256) void pool2_kernel(const float* __restrict__ q,
                                                    float* __restrict__ out) {
    const int n = blockIdx.x; // pair index, 0..31
    const int b = blockIdx.y;
    const int tid = threadIdx.x;

    const float* K1 = out + OFF_K1;
    const float* V1 = out + OFF_V1;
    const size_t row0 = ((size_t)b * W1C + 2 * n) * NC;
    const float4 k0 = ((const float4*)(K1 + row0))[tid];
    const float4 k1 = ((const float4*)(K1 + row0 + NC))[tid];
    const float4 v0 = ((const float4*)(V1 + row0))[tid];
    const float4 v1 = ((const float4*)(V1 + row0 + NC))[tid];
    const float4 q4 = ((const float4*)(q + NC))[tid]; // q_pool[1]

    float s0 = dot4(q4, k0);
    float s1 = dot4(q4, k1);
    float4 dv = make_float4(v0.x - v1.x, v0.y - v1.y, v0.z - v1.z, v0.w - v1.w);
    float d2 = dot4(dv, dv);

#pragma unroll
    for (int off = 32; off > 0; off >>= 1) {
        s0 += __shfl_down(s0, off);
        s1 += __shfl_down(s1, off);
        d2 += __shfl_down(d2, off);
    }

    __shared__ float lds[12];
    __shared__ float wshare;
    const int lane = tid & 63, wv = tid >> 6;
    if (lane == 0) { lds[wv] = s0; lds[4 + wv] = s1; lds[8 + wv] = d2; }
    __syncthreads();
    if (tid == 0) {
        float t0 = lds[0] + lds[1] + lds[2] + lds[3];
        float t1 = lds[4] + lds[5] + lds[6] + lds[7];
        float td = lds[8] + lds[9] + lds[10] + lds[11];
        float w0 = 1.0f / (1.0f + expf(t1 - t0));
        wshare = w0;
        float dw = w0 - 0.5f;
        // total += 0.5 * recon2[n] summed; recon2[n] = dw^2*td/(B*C)
        atomicAdd(out + OFF_R, 0.5f * dw * dw * td * (1.0f / ((float)NB * NC)));
    }
    __syncthreads();

    if (n >= NPAIRS - W2C) {
        const float w0 = wshare, w1 = 1.0f - w0;
        const int nn = n - (NPAIRS - W2C);
        float4 sk = make_float4(w0 * k0.x + w1 * k1.x, w0 * k0.y + w1 * k1.y,
                                w0 * k0.z + w1 * k1.z, w0 * k0.w + w1 * k1.w);
        float4 sv = make_float4(w0 * v0.x + w1 * v1.x, w0 * v0.y + w1 * v1.y,
                                w0 * v0.z + w1 * v1.z, w0 * v0.w + w1 * v1.w);
        ((float4*)(out + OFF_K2 + ((size_t)b * W2C + nn) * NC))[tid] = sk;
        ((float4*)(out + OFF_V2 + ((size_t)b * W2C + nn) * NC))[tid] = sv;
    }
}

extern "C" void kernel_launch(void* const* d_in, const int* in_sizes, int n_in,
                              void* d_out, int out_size, void* d_ws, size_t ws_size,
                              hipStream_t stream) {
    const float* K = (const float*)d_in[0];
    const float* V = (const float*)d_in[1];
    const float* q = (const float*)d_in[2];
    float* out = (float*)d_out;

    // zero the recon accumulator (graph-capture-safe async memset)
    hipMemsetAsync((char*)d_out + (size_t)OFF_R * sizeof(float), 0, sizeof(float), stream);

    copy0_kernel<<<dim3(2 * NB * W0C * NC / 4 / 256), 256, 0, stream>>>(K, V, out);
    pool1_kernel<<<dim3(NCHUNKS, NB), 256, 0, stream>>>(K, V, q, out);
    pool2_kernel<<<dim3(NPAIRS, NB), 256, 0, stream>>>(q, out);
}

// Round 2
// 66.673 us; speedup vs baseline: 3.4108x; 3.4108x over previous
//
#include <hip/hip_runtime.h>

// Problem constants (from setup_inputs: B=4, T=8192, C=1024, stride=2)
#define NB 4
#define NT 8192
#define NC 1024
#define W0C 128
#define W1C 64
#define W2C 16
#define NCHUNKS ((NT - W0C) / 2) // 4032
#define NPAIRS (W1C / 2)         // 32

// Output layout (flat f32 offsets): K0,V0,K1,V1,K2,V2,total_recon
#define OFF_K0 0
#define OFF_V0 (NB * W0C * NC)             // 524288
#define OFF_K1 (2 * NB * W0C * NC)         // 1048576
#define OFF_V1 (OFF_K1 + NB * W1C * NC)    // 1310720
#define OFF_K2 (OFF_V1 + NB * W1C * NC)    // 1572864
#define OFF_V2 (OFF_K2 + NB * W2C * NC)    // 1638400
#define OFF_R  (OFF_V2 + NB * W2C * NC)    // 1703936

// Workspace layout (floats): [0, NB*NCHUNKS) pool1 partials, then NB*NPAIRS pool2 partials
#define WS_P2 (NB * NCHUNKS) // 16128

__device__ __forceinline__ float dot4(float4 a, float4 b) {
    return a.x * b.x + a.y * b.y + a.z * b.z + a.w * b.w;
}

// K0/V0: copy last W0 rows of K and V. 2 * B*W0*C/4 float4s = 262144.
__global__ __launch_bounds__(256) void copy0_kernel(const float* __restrict__ K,
                                                    const float* __restrict__ V,
                                                    float* __restrict__ out) {
    int idx = blockIdx.x * 256 + threadIdx.x; // float4 index
    const int half = NB * W0C * NC / 4;       // 131072
    const float* src;
    float* dst;
    int i;
    if (idx < half) { src = K; dst = out + OFF_K0; i = idx; }
    else            { src = V; dst = out + OFF_V0; i = idx - half; }
    const int per_b = W0C * NC / 4; // 32768 float4 per batch
    int b = i / per_b;
    int r = i - b * per_b;
    const float4* s4 = (const float4*)(src + ((size_t)b * NT + (NT - W0C)) * NC);
    ((float4*)dst)[i] = s4[r];
}

// Level-1 pool: one WAVE per (b, n) chunk; 4 waves (4 chunks) per block.
// Each lane owns 16 channels as 4 float4s strided by 64 for coalescing.
// No __syncthreads, no LDS, no atomics: partial recon goes to d_ws.
__global__ __launch_bounds__(256) void pool1_kernel(const float* __restrict__ K,
                                                    const float* __restrict__ V,
                                                    const float* __restrict__ q,
                                                    float* __restrict__ out,
                                                    float* __restrict__ ws) {
    const int wv = threadIdx.x >> 6;
    const int lane = threadIdx.x & 63;
    const int n = blockIdx.x * 4 + wv;
    const int b = blockIdx.y;

    const size_t row0 = ((size_t)b * NT + 2 * n) * NC;
    const float4* Kp0 = (const float4*)(K + row0);
    const float4* Kp1 = (const float4*)(K + row0 + NC);
    const float4* Vp0 = (const float4*)(V + row0);
    const float4* Vp1 = (const float4*)(V + row0 + NC);
    const float4* q4 = (const float4*)q;

    float4 k0[4], k1[4], v0[4], v1[4], qv[4];
#pragma unroll
    for (int j = 0; j < 4; j++) {
        const int idx = lane + 64 * j;
        k0[j] = Kp0[idx]; k1[j] = Kp1[idx];
        v0[j] = Vp0[idx]; v1[j] = Vp1[idx];
        qv[j] = q4[idx];
    }

    float s0 = 0.f, s1 = 0.f, d2 = 0.f;
#pragma unroll
    for (int j = 0; j < 4; j++) {
        s0 += dot4(qv[j], k0[j]);
        s1 += dot4(qv[j], k1[j]);
        float4 dv = make_float4(v0[j].x - v1[j].x, v0[j].y - v1[j].y,
                                v0[j].z - v1[j].z, v0[j].w - v1[j].w);
        d2 += dot4(dv, dv);
    }

    // Butterfly reduce over the 64-lane wave: all lanes end with the totals.
#pragma unroll
    for (int off = 1; off < 64; off <<= 1) {
        s0 += __shfl_xor(s0, off);
        s1 += __shfl_xor(s1, off);
        d2 += __shfl_xor(d2, off);
    }

    const float w0 = 1.0f / (1.0f + __expf(s1 - s0)); // softmax over 2
    if (lane == 0) {
        const float dw = w0 - 0.5f;
        ws[b * NCHUNKS + n] = dw * dw * d2; // unscaled partial; scaled in reduce
    }

    if (n >= NCHUNKS - W1C) {
        const float w1 = 1.0f - w0;
        const int nn = n - (NCHUNKS - W1C);
        float4* skp = (float4*)(out + OFF_K1 + ((size_t)b * W1C + nn) * NC);
        float4* svp = (float4*)(out + OFF_V1 + ((size_t)b * W1C + nn) * NC);
#pragma unroll
        for (int j = 0; j < 4; j++) {
            const int idx = lane + 64 * j;
            skp[idx] = make_float4(w0 * k0[j].x + w1 * k1[j].x, w0 * k0[j].y + w1 * k1[j].y,
                                   w0 * k0[j].z + w1 * k1[j].z, w0 * k0[j].w + w1 * k1[j].w);
            svp[idx] = make_float4(w0 * v0[j].x + w1 * v1[j].x, w0 * v0[j].y + w1 * v1[j].y,
                                   w0 * v0[j].z + w1 * v1[j].z, w0 * v0[j].w + w1 * v1[j].w);
        }
    }
}

// Level-2 pool: one wave per pair; reads K1/V1 from out (stream-ordered after pool1).
__global__ __launch_bounds__(64) void pool2_kernel(const float* __restrict__ q,
                                                   float* __restrict__ out,
                                                   float* __restrict__ ws) {
    const int n = blockIdx.x; // pair index, 0..31
    const int b = blockIdx.y;
    const int lane = threadIdx.x & 63;

    const float* K1 = out + OFF_K1;
    const float* V1 = out + OFF_V1;
    const size_t row0 = ((size_t)b * W1C + 2 * n) * NC;
    const float4* Kp0 = (const float4*)(K1 + row0);
    const float4* Kp1 = (const float4*)(K1 + row0 + NC);
    const float4* Vp0 = (const float4*)(V1 + row0);
    const float4* Vp1 = (const float4*)(V1 + row0 + NC);
    const float4* q4 = (const float4*)(q + NC); // q_pool[1]

    float4 k0[4], k1[4], v0[4], v1[4], qv[4];
#pragma unroll
    for (int j = 0; j < 4; j++) {
        const int idx = lane + 64 * j;
        k0[j] = Kp0[idx]; k1[j] = Kp1[idx];
        v0[j] = Vp0[idx]; v1[j] = Vp1[idx];
        qv[j] = q4[idx];
    }

    float s0 = 0.f, s1 = 0.f, d2 = 0.f;
#pragma unroll
    for (int j = 0; j < 4; j++) {
        s0 += dot4(qv[j], k0[j]);
        s1 += dot4(qv[j], k1[j]);
        float4 dv = make_float4(v0[j].x - v1[j].x, v0[j].y - v1[j].y,
                                v0[j].z - v1[j].z, v0[j].w - v1[j].w);
        d2 += dot4(dv, dv);
    }

#pragma unroll
    for (int off = 1; off < 64; off <<= 1) {
        s0 += __shfl_xor(s0, off);
        s1 += __shfl_xor(s1, off);
        d2 += __shfl_xor(d2, off);
    }

    const float w0 = 1.0f / (1.0f + __expf(s1 - s0));
    if (lane == 0) {
        const float dw = w0 - 0.5f;
        ws[WS_P2 + b * NPAIRS + n] = dw * dw * d2;
    }

    if (n >= NPAIRS - W2C) {
        const float w1 = 1.0f - w0;
        const int nn = n - (NPAIRS - W2C);
        float4* skp = (float4*)(out + OFF_K2 + ((size_t)b * W2C + nn) * NC);
        float4* svp = (float4*)(out + OFF_V2 + ((size_t)b * W2C + nn) * NC);
#pragma unroll
        for (int j = 0; j < 4; j++) {
            const int idx = lane + 64 * j;
            skp[idx] = make_float4(w0 * k0[j].x + w1 * k1[j].x, w0 * k0[j].y + w1 * k1[j].y,
                                   w0 * k0[j].z + w1 * k1[j].z, w0 * k0[j].w + w1 * k1[j].w);
            svp[idx] = make_float4(w0 * v0[j].x + w1 * v1[j].x, w0 * v0[j].y + w1 * v1[j].y,
                                   w0 * v0[j].z + w1 * v1[j].z, w0 * v0[j].w + w1 * v1[j].w);
        }
    }
}

// Final reduce: one block sums all partials and writes total_recon.
__global__ __launch_bounds__(256) void reduce_kernel(const float* __restrict__ ws,
                                                     float* __restrict__ out) {
    const int tid = threadIdx.x;
    float acc1 = 0.f;
    for (int i = tid; i < WS_P2; i += 256) acc1 += ws[i];
    float acc2 = 0.f;
    for (int i = tid; i < NB * NPAIRS; i += 256) acc2 += ws[WS_P2 + i];

    const float S1 = 1.0f / ((float)NB * NC * NCHUNKS);
    const float S2 = 0.5f / ((float)NB * NC);
    float acc = acc1 * S1 + acc2 * S2;

#pragma unroll
    for (int off = 32; off > 0; off >>= 1) acc += __shfl_down(acc, off);

    __shared__ float lds[4];
    if ((tid & 63) == 0) lds[tid >> 6] = acc;
    __syncthreads();
    if (tid == 0) out[OFF_R] = lds[0] + lds[1] + lds[2] + lds[3];
}

extern "C" void kernel_launch(void* const* d_in, const int* in_sizes, int n_in,
                              void* d_out, int out_size, void* d_ws, size_t ws_size,
                              hipStream_t stream) {
    const float* K = (const float*)d_in[0];
    const float* V = (const float*)d_in[1];
    const float* q = (const float*)d_in[2];
    float* out = (float*)d_out;
    float* ws = (float*)d_ws;

    copy0_kernel<<<dim3(2 * NB * W0C * NC / 4 / 256), 256, 0, stream>>>(K, V, out);
    pool1_kernel<<<dim3(NCHUNKS / 4, NB), 256, 0, stream>>>(K, V, q, out, ws);
    pool2_kernel<<<dim3(NPAIRS, NB), 64, 0, stream>>>(q, out, ws);
    reduce_kernel<<<1, 256, 0, stream>>>(ws, out);
}

// Round 3
// 64.322 us; speedup vs baseline: 3.5355x; 1.0366x over previous
//
#include <hip/hip_runtime.h>

// Problem constants (from setup_inputs: B=4, T=8192, C=1024, stride=2)
#define NB 4
#define NT 8192
#define NC 1024
#define W0C 128
#define W1C 64
#define W2C 16
#define NCHUNKS ((NT - W0C) / 2) // 4032
#define NPAIRS (W1C / 2)         // 32

// Output layout (flat f32 offsets): K0,V0,K1,V1,K2,V2,total_recon
#define OFF_K0 0
#define OFF_V0 (NB * W0C * NC)             // 524288
#define OFF_K1 (2 * NB * W0C * NC)         // 1048576
#define OFF_V1 (OFF_K1 + NB * W1C * NC)    // 1310720
#define OFF_K2 (OFF_V1 + NB * W1C * NC)    // 1572864
#define OFF_V2 (OFF_K2 + NB * W2C * NC)    // 1638400
#define OFF_R  (OFF_V2 + NB * W2C * NC)    // 1703936

// Workspace layout (floats): [0, NB*NCHUNKS) pool1 partials, then NB*NPAIRS pool2 partials
#define WS_P2 (NB * NCHUNKS) // 16128

#define P1_BLOCKS (NCHUNKS / 4) // 1008 pool blocks per batch row
#define CP_BLOCKS 256           // 2*W0C*NC/4/256 = copy blocks per batch

__device__ __forceinline__ float dot4(float4 a, float4 b) {
    return a.x * b.x + a.y * b.y + a.z * b.z + a.w * b.w;
}

// Fused: blockIdx.x < P1_BLOCKS -> level-1 pool (4 waves = 4 chunks);
//        else -> K0/V0 tail copy for this batch.
// launch_bounds(256,4): allow up to 128 VGPRs so all 16 payload loads are in
// flight before the first s_waitcnt (round-2's 48-VGPR build serialized them
// into 4 batches -> 4 memory round trips per wave, latency-bound at 2.8 TB/s).
__global__ __launch_bounds__(256, 4) void pool1_kernel(const float* __restrict__ K,
                                                       const float* __restrict__ V,
                                                       const float* __restrict__ q,
                                                       float* __restrict__ out,
                                                       float* __restrict__ ws) {
    const int b = blockIdx.y;

    if (blockIdx.x >= P1_BLOCKS) {
        // ---- copy K0/V0 (last W0 rows) for batch b ----
        const int i = (blockIdx.x - P1_BLOCKS) * 256 + threadIdx.x; // float4 idx in batch
        const int half = W0C * NC / 4;                              // 32768
        const float* src;
        float* dst;
        int r;
        if (i < half) { src = K; dst = out + OFF_K0; r = i; }
        else          { src = V; dst = out + OFF_V0; r = i - half; }
        const float4* s4 = (const float4*)(src + ((size_t)b * NT + (NT - W0C)) * NC);
        ((float4*)(dst + (size_t)b * W0C * NC))[r] = s4[r];
        return;
    }

    const int wv = threadIdx.x >> 6;
    const int lane = threadIdx.x & 63;
    const int n = blockIdx.x * 4 + wv;

    const size_t row0 = ((size_t)b * NT + 2 * n) * NC;
    const float4* Kp0 = (const float4*)(K + row0);
    const float4* Kp1 = (const float4*)(K + row0 + NC);
    const float4* Vp0 = (const float4*)(V + row0);
    const float4* Vp1 = (const float4*)(V + row0 + NC);
    const float4* q4 = (const float4*)q;

    // Issue ALL payload loads first (k then v), then q (L2-hot), then consume.
    float4 k0[4], k1[4], v0[4], v1[4], qv[4];
#pragma unroll
    for (int j = 0; j < 4; j++) {
        const int idx = lane + 64 * j;
        k0[j] = Kp0[idx]; k1[j] = Kp1[idx];
        v0[j] = Vp0[idx]; v1[j] = Vp1[idx];
    }
#pragma unroll
    for (int j = 0; j < 4; j++) qv[j] = q4[lane + 64 * j];

    float s0 = 0.f, s1 = 0.f, d2 = 0.f;
#pragma unroll
    for (int j = 0; j < 4; j++) {
        s0 += dot4(qv[j], k0[j]);
        s1 += dot4(qv[j], k1[j]);
        float4 dv = make_float4(v0[j].x - v1[j].x, v0[j].y - v1[j].y,
                                v0[j].z - v1[j].z, v0[j].w - v1[j].w);
        d2 += dot4(dv, dv);
    }

    // Butterfly reduce across the wave; all lanes end with totals.
#pragma unroll
    for (int off = 1; off < 64; off <<= 1) {
        s0 += __shfl_xor(s0, off);
        s1 += __shfl_xor(s1, off);
        d2 += __shfl_xor(d2, off);
    }

    const float w0 = 1.0f / (1.0f + __expf(s1 - s0)); // softmax over 2
    if (lane == 0) {
        const float dw = w0 - 0.5f;
        ws[b * NCHUNKS + n] = dw * dw * d2; // unscaled; scaled in reduce
    }

    if (n >= NCHUNKS - W1C) {
        // Rare tail (256 of 16128 waves): RELOAD rows from cache so k/v arrays
        // are dead after the FMA chain for the common path (keeps VGPR <= 128).
        const float w1 = 1.0f - w0;
        const int nn = n - (NCHUNKS - W1C);
        float4* skp = (float4*)(out + OFF_K1 + ((size_t)b * W1C + nn) * NC);
        float4* svp = (float4*)(out + OFF_V1 + ((size_t)b * W1C + nn) * NC);
#pragma unroll
        for (int j = 0; j < 4; j++) {
            const int idx = lane + 64 * j;
            float4 a0 = Kp0[idx], a1 = Kp1[idx];
            float4 c0 = Vp0[idx], c1 = Vp1[idx];
            skp[idx] = make_float4(w0 * a0.x + w1 * a1.x, w0 * a0.y + w1 * a1.y,
                                   w0 * a0.z + w1 * a1.z, w0 * a0.w + w1 * a1.w);
            svp[idx] = make_float4(w0 * c0.x + w1 * c1.x, w0 * c0.y + w1 * c1.y,
                                   w0 * c0.z + w1 * c1.z, w0 * c0.w + w1 * c1.w);
        }
    }
}

// Level-2 pool: one wave per pair; reads K1/V1 from out (stream-ordered after pool1).
__global__ __launch_bounds__(64) void pool2_kernel(const float* __restrict__ q,
                                                   float* __restrict__ out,
                                                   float* __restrict__ ws) {
    const int n = blockIdx.x; // pair index, 0..31
    const int b = blockIdx.y;
    const int lane = threadIdx.x & 63;

    const float* K1 = out + OFF_K1;
    const float* V1 = out + OFF_V1;
    const size_t row0 = ((size_t)b * W1C + 2 * n) * NC;
    const float4* Kp0 = (const float4*)(K1 + row0);
    const float4* Kp1 = (const float4*)(K1 + row0 + NC);
    const float4* Vp0 = (const float4*)(V1 + row0);
    const float4* Vp1 = (const float4*)(V1 + row0 + NC);
    const float4* q4 = (const float4*)(q + NC); // q_pool[1]

    float4 k0[4], k1[4], v0[4], v1[4], qv[4];
#pragma unroll
    for (int j = 0; j < 4; j++) {
        const int idx = lane + 64 * j;
        k0[j] = Kp0[idx]; k1[j] = Kp1[idx];
        v0[j] = Vp0[idx]; v1[j] = Vp1[idx];
        qv[j] = q4[idx];
    }

    float s0 = 0.f, s1 = 0.f, d2 = 0.f;
#pragma unroll
    for (int j = 0; j < 4; j++) {
        s0 += dot4(qv[j], k0[j]);
        s1 += dot4(qv[j], k1[j]);
        float4 dv = make_float4(v0[j].x - v1[j].x, v0[j].y - v1[j].y,
                                v0[j].z - v1[j].z, v0[j].w - v1[j].w);
        d2 += dot4(dv, dv);
    }

#pragma unroll
    for (int off = 1; off < 64; off <<= 1) {
        s0 += __shfl_xor(s0, off);
        s1 += __shfl_xor(s1, off);
        d2 += __shfl_xor(d2, off);
    }

    const float w0 = 1.0f / (1.0f + __expf(s1 - s0));
    if (lane == 0) {
        const float dw = w0 - 0.5f;
        ws[WS_P2 + b * NPAIRS + n] = dw * dw * d2;
    }

    if (n >= NPAIRS - W2C) {
        const float w1 = 1.0f - w0;
        const int nn = n - (NPAIRS - W2C);
        float4* skp = (float4*)(out + OFF_K2 + ((size_t)b * W2C + nn) * NC);
        float4* svp = (float4*)(out + OFF_V2 + ((size_t)b * W2C + nn) * NC);
#pragma unroll
        for (int j = 0; j < 4; j++) {
            const int idx = lane + 64 * j;
            skp[idx] = make_float4(w0 * k0[j].x + w1 * k1[j].x, w0 * k0[j].y + w1 * k1[j].y,
                                   w0 * k0[j].z + w1 * k1[j].z, w0 * k0[j].w + w1 * k1[j].w);
            svp[idx] = make_float4(w0 * v0[j].x + w1 * v1[j].x, w0 * v0[j].y + w1 * v1[j].y,
                                   w0 * v0[j].z + w1 * v1[j].z, w0 * v0[j].w + w1 * v1[j].w);
        }
    }
}

// Final reduce: one block sums all partials and writes total_recon.
__global__ __launch_bounds__(256) void reduce_kernel(const float* __restrict__ ws,
                                                     float* __restrict__ out) {
    const int tid = threadIdx.x;
    float acc1 = 0.f;
    for (int i = tid; i < WS_P2; i += 256) acc1 += ws[i];
    float acc2 = 0.f;
    for (int i = tid; i < NB * NPAIRS; i += 256) acc2 += ws[WS_P2 + i];

    const float S1 = 1.0f / ((float)NB * NC * NCHUNKS);
    const float S2 = 0.5f / ((float)NB * NC);
    float acc = acc1 * S1 + acc2 * S2;

#pragma unroll
    for (int off = 32; off > 0; off >>= 1) acc += __shfl_down(acc, off);

    __shared__ float lds[4];
    if ((tid & 63) == 0) lds[tid >> 6] = acc;
    __syncthreads();
    if (tid == 0) out[OFF_R] = lds[0] + lds[1] + lds[2] + lds[3];
}

extern "C" void kernel_launch(void* const* d_in, const int* in_sizes, int n_in,
                              void* d_out, int out_size, void* d_ws, size_t ws_size,
                              hipStream_t stream) {
    const float* K = (const float*)d_in[0];
    const float* V = (const float*)d_in[1];
    const float* q = (const float*)d_in[2];
    float* out = (float*)d_out;
    float* ws = (float*)d_ws;

    pool1_kernel<<<dim3(P1_BLOCKS + CP_BLOCKS, NB), 256, 0, stream>>>(K, V, q, out, ws);
    pool2_kernel<<<dim3(NPAIRS, NB), 64, 0, stream>>>(q, out, ws);
    reduce_kernel<<<1, 256, 0, stream>>>(ws, out);
}

// Round 4
// 63.361 us; speedup vs baseline: 3.5891x; 1.0152x over previous
//
#include <hip/hip_runtime.h>

// Problem constants (from setup_inputs: B=4, T=8192, C=1024, stride=2)
#define NB 4
#define NT 8192
#define NC 1024
#define W0C 128
#define W1C 64
#define W2C 16
#define NCHUNKS ((NT - W0C) / 2) // 4032
#define NPAIRS (W1C / 2)         // 32

// Output layout (flat f32 offsets): K0,V0,K1,V1,K2,V2,total_recon
#define OFF_K0 0
#define OFF_V0 (NB * W0C * NC)             // 524288
#define OFF_K1 (2 * NB * W0C * NC)         // 1048576
#define OFF_V1 (OFF_K1 + NB * W1C * NC)    // 1310720
#define OFF_K2 (OFF_V1 + NB * W1C * NC)    // 1572864
#define OFF_V2 (OFF_K2 + NB * W2C * NC)    // 1638400
#define OFF_R  (OFF_V2 + NB * W2C * NC)    // 1703936

// Workspace layout (floats): [0, NB*NCHUNKS) pool1 partials, then NB*NPAIRS pool2 partials
#define WS_P2 (NB * NCHUNKS) // 16128

#define CP_BLOCKS 256 // 2*W0C*NC/4/256 float4-copy blocks per batch

__device__ __forceinline__ float dot4(float4 a, float4 b) {
    return a.x * b.x + a.y * b.y + a.z * b.z + a.w * b.w;
}

// Thin-thread level-1 pool: one BLOCK per chunk, one float4 per array per
// thread. Each thread has exactly 5 independent loads (k0,k1,v0,v1,q) that
// fit in ~24 VGPRs -> all issue in ONE waitcnt batch -> one memory round trip
// per wave (round-3's fat-thread shape was forced into ~5 serialized batches).
// Low VGPR -> 8 waves/SIMD resident -> ~160 KB in flight per CU (Little's law
// saturation). blockIdx.x >= NCHUNKS handles the K0/V0 tail copy.
__global__ __launch_bounds__(256) void pool1_kernel(const float* __restrict__ K,
                                                    const float* __restrict__ V,
                                                    const float* __restrict__ q,
                                                    float* __restrict__ out,
                                                    float* __restrict__ ws) {
    const int b = blockIdx.y;

    if (blockIdx.x >= NCHUNKS) {
        // ---- copy K0/V0 (last W0 rows) for batch b ----
        const int i = (blockIdx.x - NCHUNKS) * 256 + threadIdx.x; // float4 idx in batch
        const int half = W0C * NC / 4;                            // 32768
        const float* src;
        float* dst;
        int r;
        if (i < half) { src = K; dst = out + OFF_K0; r = i; }
        else          { src = V; dst = out + OFF_V0; r = i - half; }
        const float4* s4 = (const float4*)(src + ((size_t)b * NT + (NT - W0C)) * NC);
        ((float4*)(dst + (size_t)b * W0C * NC))[r] = s4[r];
        return;
    }

    const int n = blockIdx.x;
    const int t = threadIdx.x;

    const size_t row0 = ((size_t)b * NT + 2 * n) * NC;
    const float4 k0 = ((const float4*)(K + row0))[t];
    const float4 k1 = ((const float4*)(K + row0 + NC))[t];
    const float4 v0 = ((const float4*)(V + row0))[t];
    const float4 v1 = ((const float4*)(V + row0 + NC))[t];
    const float4 q4 = ((const float4*)q)[t];

    float s0 = dot4(q4, k0);
    float s1 = dot4(q4, k1);
    const float4 dv = make_float4(v0.x - v1.x, v0.y - v1.y, v0.z - v1.z, v0.w - v1.w);
    float d2 = dot4(dv, dv);

    // Wave butterfly, then cross-wave combine via 12 LDS floats.
#pragma unroll
    for (int off = 1; off < 64; off <<= 1) {
        s0 += __shfl_xor(s0, off);
        s1 += __shfl_xor(s1, off);
        d2 += __shfl_xor(d2, off);
    }

    __shared__ float lds[12];
    const int lane = t & 63, wv = t >> 6;
    if (lane == 0) { lds[wv] = s0; lds[4 + wv] = s1; lds[8 + wv] = d2; }
    __syncthreads();
    // All threads read the 12 totals (same-address LDS broadcasts, no conflict)
    const float t0 = lds[0] + lds[1] + lds[2] + lds[3];
    const float t1 = lds[4] + lds[5] + lds[6] + lds[7];
    const float td = lds[8] + lds[9] + lds[10] + lds[11];
    const float w0 = 1.0f / (1.0f + __expf(t1 - t0)); // softmax over 2

    if (t == 0) {
        const float dw = w0 - 0.5f;
        ws[b * NCHUNKS + n] = dw * dw * td; // unscaled; scaled in reduce
    }

    if (n >= NCHUNKS - W1C) {
        const float w1 = 1.0f - w0;
        const int nn = n - (NCHUNKS - W1C);
        float4* skp = (float4*)(out + OFF_K1 + ((size_t)b * W1C + nn) * NC);
        float4* svp = (float4*)(out + OFF_V1 + ((size_t)b * W1C + nn) * NC);
        skp[t] = make_float4(w0 * k0.x + w1 * k1.x, w0 * k0.y + w1 * k1.y,
                             w0 * k0.z + w1 * k1.z, w0 * k0.w + w1 * k1.w);
        svp[t] = make_float4(w0 * v0.x + w1 * v1.x, w0 * v0.y + w1 * v1.y,
                             w0 * v0.z + w1 * v1.z, w0 * v0.w + w1 * v1.w);
    }
}

// Level-2 pool: one wave per pair; reads K1/V1 from out (stream-ordered after pool1).
__global__ __launch_bounds__(64) void pool2_kernel(const float* __restrict__ q,
                                                   float* __restrict__ out,
                                                   float* __restrict__ ws) {
    const int n = blockIdx.x; // pair index, 0..31
    const int b = blockIdx.y;
    const int lane = threadIdx.x & 63;

    const float* K1 = out + OFF_K1;
    const float* V1 = out + OFF_V1;
    const size_t row0 = ((size_t)b * W1C + 2 * n) * NC;
    const float4* Kp0 = (const float4*)(K1 + row0);
    const float4* Kp1 = (const float4*)(K1 + row0 + NC);
    const float4* Vp0 = (const float4*)(V1 + row0);
    const float4* Vp1 = (const float4*)(V1 + row0 + NC);
    const float4* q4 = (const float4*)(q + NC); // q_pool[1]

    float4 k0[4], k1[4], v0[4], v1[4], qv[4];
#pragma unroll
    for (int j = 0; j < 4; j++) {
        const int idx = lane + 64 * j;
        k0[j] = Kp0[idx]; k1[j] = Kp1[idx];
        v0[j] = Vp0[idx]; v1[j] = Vp1[idx];
        qv[j] = q4[idx];
    }

    float s0 = 0.f, s1 = 0.f, d2 = 0.f;
#pragma unroll
    for (int j = 0; j < 4; j++) {
        s0 += dot4(qv[j], k0[j]);
        s1 += dot4(qv[j], k1[j]);
        float4 dv = make_float4(v0[j].x - v1[j].x, v0[j].y - v1[j].y,
                                v0[j].z - v1[j].z, v0[j].w - v1[j].w);
        d2 += dot4(dv, dv);
    }

#pragma unroll
    for (int off = 1; off < 64; off <<= 1) {
        s0 += __shfl_xor(s0, off);
        s1 += __shfl_xor(s1, off);
        d2 += __shfl_xor(d2, off);
    }

    const float w0 = 1.0f / (1.0f + __expf(s1 - s0));
    if (lane == 0) {
        const float dw = w0 - 0.5f;
        ws[WS_P2 + b * NPAIRS + n] = dw * dw * d2;
    }

    if (n >= NPAIRS - W2C) {
        const float w1 = 1.0f - w0;
        const int nn = n - (NPAIRS - W2C);
        float4* skp = (float4*)(out + OFF_K2 + ((size_t)b * W2C + nn) * NC);
        float4* svp = (float4*)(out + OFF_V2 + ((size_t)b * W2C + nn) * NC);
#pragma unroll
        for (int j = 0; j < 4; j++) {
            const int idx = lane + 64 * j;
            skp[idx] = make_float4(w0 * k0[j].x + w1 * k1[j].x, w0 * k0[j].y + w1 * k1[j].y,
                                   w0 * k0[j].z + w1 * k1[j].z, w0 * k0[j].w + w1 * k1[j].w);
            svp[idx] = make_float4(w0 * v0[j].x + w1 * v1[j].x, w0 * v0[j].y + w1 * v1[j].y,
                                   w0 * v0[j].z + w1 * v1[j].z, w0 * v0[j].w + w1 * v1[j].w);
        }
    }
}

// Final reduce: one block sums all partials and writes total_recon.
__global__ __launch_bounds__(256) void reduce_kernel(const float* __restrict__ ws,
                                                     float* __restrict__ out) {
    const int tid = threadIdx.x;
    float acc1 = 0.f;
    for (int i = tid; i < WS_P2; i += 256) acc1 += ws[i];
    float acc2 = 0.f;
    for (int i = tid; i < NB * NPAIRS; i += 256) acc2 += ws[WS_P2 + i];

    const float S1 = 1.0f / ((float)NB * NC * NCHUNKS);
    const float S2 = 0.5f / ((float)NB * NC);
    float acc = acc1 * S1 + acc2 * S2;

#pragma unroll
    for (int off = 32; off > 0; off >>= 1) acc += __shfl_down(acc, off);

    __shared__ float lds[4];
    if ((tid & 63) == 0) lds[tid >> 6] = acc;
    __syncthreads();
    if (tid == 0) out[OFF_R] = lds[0] + lds[1] + lds[2] + lds[3];
}

extern "C" void kernel_launch(void* const* d_in, const int* in_sizes, int n_in,
                              void* d_out, int out_size, void* d_ws, size_t ws_size,
                              hipStream_t stream) {
    const float* K = (const float*)d_in[0];
    const float* V = (const float*)d_in[1];
    const float* q = (const float*)d_in[2];
    float* out = (float*)d_out;
    float* ws = (float*)d_ws;

    pool1_kernel<<<dim3(NCHUNKS + CP_BLOCKS, NB), 256, 0, stream>>>(K, V, q, out, ws);
    pool2_kernel<<<dim3(NPAIRS, NB), 64, 0, stream>>>(q, out, ws);
    reduce_kernel<<<1, 256, 0, stream>>>(ws, out);
}